// Round 10
// baseline (189.137 us; speedup 1.0000x reference)
//
#include <hip/hip_runtime.h>
#include <math.h>

typedef unsigned short u16;
typedef unsigned int u32;
typedef __attribute__((ext_vector_type(8))) short bf16x8;   // 8 bf16 = 4 VGPR (MFMA A/B frag)
typedef __attribute__((ext_vector_type(4))) float f32x4;    // MFMA C/D frag

__device__ __forceinline__ u16 f32_to_bf16(float f) {
    u32 u = __float_as_uint(f);
    u32 r = u + 0x7FFFu + ((u >> 16) & 1u);   // round-to-nearest-even
    return (u16)(r >> 16);
}
__device__ __forceinline__ float bf16_to_f32(u16 h) {
    return __uint_as_float(((u32)h) << 16);
}
__device__ __forceinline__ u32 pack2(u16 a, u16 b) { return (u32)a | ((u32)b << 16); }

// RNE-rounded bf16 pair pack via v_perm
__device__ __forceinline__ u32 rne_bits(float f) {
    u32 u = __float_as_uint(f);
    return u + 0x7FFFu + ((u >> 16) & 1u);
}
__device__ __forceinline__ u32 pack_rne(float a, float b) {
    return __builtin_amdgcn_perm(rne_bits(b), rne_bits(a), 0x07060302u);
}

// ---------------- quantum gate helpers ----------------
template<int STRIDE>
__device__ __forceinline__ void ry_gate(float st[16], float theta) {
    float s, c;
    sincosf(theta * 0.5f, &s, &c);
#pragma unroll
    for (int i = 0; i < 16; ++i) {
        if (i & STRIDE) continue;
        float s0 = st[i], s1 = st[i | STRIDE];
        st[i]          = c * s0 - s * s1;
        st[i | STRIDE] = fmaf(s, s0, c * s1);
    }
}
template<int CS, int TS>
__device__ __forceinline__ void cnot_gate(float st[16]) {
#pragma unroll
    for (int i = 0; i < 16; ++i) {
        if ((i & CS) && !(i & TS)) {
            float tmp = st[i]; st[i] = st[i | TS]; st[i | TS] = tmp;
        }
    }
}

// ---------------- Prep: fcw transpose+split, w2->bf16 frag layout, circuit matrix M ----------
__global__ __launch_bounds__(256) void prep_kernel(
    const float* __restrict__ fcw, const float* __restrict__ w2,
    const float* __restrict__ qp,
    u16* __restrict__ whi, u16* __restrict__ wlo,
    u16* __restrict__ w2b, float* __restrict__ Mg)
{
    const int f  = blockIdx.x;         // 0..63
    const int k0 = threadIdx.x * 4;    // 0..1020
    u16 hv[4], lv[4];
#pragma unroll
    for (int i = 0; i < 4; ++i) {
        int k  = k0 + i;
        int op = k >> 6, oc = k & 63;
        float v = fcw[(size_t)(oc * 16 + op) * 64 + f];
        u16 hb = f32_to_bf16(v);
        hv[i] = hb;
        lv[i] = f32_to_bf16(v - bf16_to_f32(hb));
    }
    *(uint2*)(whi + (size_t)f * 1024 + k0) = make_uint2(pack2(hv[0], hv[1]), pack2(hv[2], hv[3]));
    *(uint2*)(wlo + (size_t)f * 1024 + k0) = make_uint2(pack2(lv[0], lv[1]), pack2(lv[2], lv[3]));

    if (threadIdx.x < 96) {
        const int j  = threadIdx.x;
        const int ic = j / 3, t = j - ic * 3;
        w2b[(t * 64 + f) * 32 + ic] = f32_to_bf16(w2[f * 96 + j]);
    }

    if (blockIdx.x == 0 && threadIdx.x < 16) {
        const int j = threadIdx.x;
        float st[16];
#pragma unroll
        for (int i = 0; i < 16; ++i) st[i] = (i == j) ? 1.f : 0.f;
        for (int k = 0; k < 6; ++k) {
            cnot_gate<8, 4>(st);   // CNOT(0,1)
            cnot_gate<2, 1>(st);   // CNOT(2,3)
            cnot_gate<4, 2>(st);   // CNOT(1,2)
            ry_gate<8>(st, qp[k * 4 + 0]);
            ry_gate<4>(st, qp[k * 4 + 1]);
            ry_gate<2>(st, qp[k * 4 + 2]);
            ry_gate<1>(st, qp[k * 4 + 3]);
        }
#pragma unroll
        for (int i = 0; i < 16; ++i) Mg[i * 16 + j] = st[i];
    }
}

// ---------------- Fused: conv1 -> conv2(MFMA) -> fc(MFMA, K-split x16 waves) -> epilogue -------
// 32 samples/block, 1024 blocks, 1024 threads (16 waves), ~99.4 KB LDS -> 1 block/CU.
// __launch_bounds__(1024,4) -> VGPR cap 128 (R8-proven: no spill; WRITE_SIZE must stay ~0.13 MB).
// Per-sample block in c1h (1384 u16): c1T rows p[0,34) stride 40 (halo rows 0,33 zero);
// hT aliased (in-wave read-before-write) op-chunk stride 72; hfl f32[64] at u16 offset 1152.
__global__ __launch_bounds__(1024, 4) void fused_kernel(
    const float* __restrict__ x,
    const float* __restrict__ w1, const float* __restrict__ b1,
    const u16* __restrict__ w2b, const float* __restrict__ b2,
    const u16* __restrict__ whi, const u16* __restrict__ wlo,
    const float* __restrict__ fcb,
    const float* __restrict__ prew, const float* __restrict__ preb,
    const float* __restrict__ postw, const float* __restrict__ postb,
    const float* __restrict__ Mg,
    float* __restrict__ out)
{
    __shared__ __align__(16) u16 c1h[32 * 1384];      // 88.6 KB
    __shared__ __align__(16) float pred[8][64][4];    // 8 KB  fc k-half partials
    __shared__ float prews[256];                      // 1 KB
    __shared__ float Ms[16][17];                      // 1.1 KB
    __shared__ float w1s[96];
    __shared__ float b1s[32];

    const int tid  = threadIdx.x;
    const int bs   = blockIdx.x * 32;
    const int wv   = tid >> 6, lane = tid & 63;
    const int lr   = lane & 15, lq = lane >> 4;

    // ---- stage small tables (incl. w1/b1 -> LDS: kills conv1's wave-uniform s_load chain) ----
    if (tid < 256) {
        prews[tid] = prew[tid];
        Ms[tid >> 4][tid & 15] = Mg[tid];
    } else if (tid < 352) {
        w1s[tid - 256] = w1[tid - 256];
    } else if (tid < 384) {
        b1s[tid - 352] = b1[tid - 352];
    }

    // ---- issue x loads pre-barrier (HBM latency drains at the barrier) ----
    const int s1 = tid >> 5;        // 0..31
    const int pp = tid & 31;        // p = pp+1
    const float* xb = x + (size_t)(bs + s1) * 64;
    const int j = 2 * pp;
    float xm1 = (j == 0)  ? 0.f : xb[j - 1];
    float x0  = xb[j];
    float x1  = xb[j + 1];
    float xp2 = (j == 62) ? 0.f : xb[j + 2];
    __syncthreads();

    // ---- conv1 + relu + pool2 -> c1T; thread = (sample, p-row), exactly 32x32 = 1024 ----
    {
        u16* sbase = c1h + s1 * 1384;
        if (pp == 0 || pp == 31) {      // halo rows 0 and 33
            uint4 z = make_uint4(0, 0, 0, 0);
            uint4* zr = (uint4*)(sbase + (pp == 0 ? 0 : 33) * 40);
            zr[0] = z; zr[1] = z; zr[2] = z; zr[3] = z;
        }
        u32 row[16];
#pragma unroll
        for (int icp = 0; icp < 16; ++icp) {
            float v[2];
#pragma unroll
            for (int h2 = 0; h2 < 2; ++h2) {
                int ic = icp * 2 + h2;
                float wa = w1s[ic * 3], wb = w1s[ic * 3 + 1], wc = w1s[ic * 3 + 2], bb = b1s[ic];
                float y0 = bb + wa * xm1 + wb * x0 + wc * x1;
                float y1 = bb + wa * x0  + wb * x1 + wc * xp2;
                v[h2] = fmaxf(fmaxf(y0, y1), 0.f);
            }
            row[icp] = pack_rne(v[0], v[1]);
        }
        uint4* d = (uint4*)(sbase + (1 + pp) * 40);
        d[0] = make_uint4(row[0],  row[1],  row[2],  row[3]);
        d[1] = make_uint4(row[4],  row[5],  row[6],  row[7]);
        d[2] = make_uint4(row[8],  row[9],  row[10], row[11]);
        d[3] = make_uint4(row[12], row[13], row[14], row[15]);
    }

    // ---- conv2 resident frags: all 3 taps (48 VGPR) + bias (16 VGPR), from L2;
    //      issued after conv1 stores so the latency overlaps the barrier wait ----
    bf16x8 af[3][4];
#pragma unroll
    for (int t = 0; t < 3; ++t)
#pragma unroll
        for (int mt = 0; mt < 4; ++mt)
            af[t][mt] = *(const bf16x8*)(w2b + (size_t)(t * 64 + mt * 16 + lr) * 32 + lq * 8);
    f32x4 bias2[4];
#pragma unroll
    for (int mt = 0; mt < 4; ++mt)
        bias2[mt] = *(const f32x4*)(b2 + mt * 16 + lq * 4);
    __syncthreads();

    // ---- conv2 via MFMA (bias as C-init) + pool -> hT aliased into c1h ----
#pragma unroll
    for (int nt = 0; nt < 4; ++nt) {              // wave wv -> samples 2wv, 2wv+1; two q-halves
        const int s  = wv * 2 + (nt >> 1);
        const int qb = (nt & 1) * 16;
        const u16* bp = c1h + s * 1384 + (qb + lr) * 40 + lq * 8;
        bf16x8 bf0 = *(const bf16x8*)(bp);        // tap t=0
        bf16x8 bf1 = *(const bf16x8*)(bp + 40);   // t=1 (+1 row)
        bf16x8 bf2 = *(const bf16x8*)(bp + 80);   // t=2 (+2 rows)
        const int op = (qb + lr) >> 1;
#pragma unroll
        for (int mt = 0; mt < 4; ++mt) {          // interleaved epilogue: acc live = 4
            f32x4 acc = __builtin_amdgcn_mfma_f32_16x16x32_bf16(af[0][mt], bf0, bias2[mt], 0, 0, 0);
            acc = __builtin_amdgcn_mfma_f32_16x16x32_bf16(af[1][mt], bf1, acc, 0, 0, 0);
            acc = __builtin_amdgcn_mfma_f32_16x16x32_bf16(af[2][mt], bf2, acc, 0, 0, 0);
            float p0 = fmaxf(fmaxf(acc[0], __shfl_xor(acc[0], 1)), 0.f);
            float p1 = fmaxf(fmaxf(acc[1], __shfl_xor(acc[1], 1)), 0.f);
            float p2 = fmaxf(fmaxf(acc[2], __shfl_xor(acc[2], 1)), 0.f);
            float p3 = fmaxf(fmaxf(acc[3], __shfl_xor(acc[3], 1)), 0.f);
            if (!(lane & 1)) {
                *(uint2*)(c1h + s * 1384 + op * 72 + mt * 16 + lq * 4) =
                    make_uint2(pack_rne(p0, p1), pack_rne(p2, p3));
            }
        }
    }
    __syncthreads();

    // ---- fc via MFMA, K-split over ALL 16 waves:
    //      wave w -> (feature tile ng = w>>2, sample tile = w&1, k-half kh = (w>>1)&1)
    //      32 MFMA + 32 B-loads each; k-halves reduced through pred[] ----
    const int ng   = wv >> 2;
    const int tile = wv & 1;
    const int kh   = (wv >> 1) & 1;
    const int n0   = ng * 16;
    const int pid  = ng * 2 + tile;
    f32x4 facc = {0.f, 0.f, 0.f, 0.f};
    {
        const u16* ab = c1h + (size_t)(tile * 16 + lr) * 1384 + lq * 8;
        const u16* bh = whi + (size_t)(n0 + lr) * 1024 + lq * 8;
        const u16* bl = wlo + (size_t)(n0 + lr) * 1024 + lq * 8;
#pragma unroll 8
        for (int kk = 0; kk < 16; ++kk) {
            const int kc = kh * 16 + kk;
            const int aoff = (kc >> 1) * 72 + (kc & 1) * 32;
            bf16x8 a  = *(const bf16x8*)(ab + aoff);
            bf16x8 fh = *(const bf16x8*)(bh + kc * 32);
            bf16x8 fl = *(const bf16x8*)(bl + kc * 32);
            facc = __builtin_amdgcn_mfma_f32_16x16x32_bf16(a, fh, facc, 0, 0, 0);
            facc = __builtin_amdgcn_mfma_f32_16x16x32_bf16(a, fl, facc, 0, 0, 0);
        }
        if (kh == 1)
            *(f32x4*)&pred[pid][lane][0] = facc;
    }
    __syncthreads();

    // ---- reduce k-halves + bias + relu -> hfl (waves with kh==0) ----
    if (kh == 0) {
        f32x4 part = *(const f32x4*)&pred[pid][lane][0];
        const float fbias = fcb[n0 + lr];
#pragma unroll
        for (int r = 0; r < 4; ++r)
            ((float*)(c1h + (size_t)(tile * 16 + lq * 4 + r) * 1384 + 1152))[n0 + lr] =
                fmaxf(facc[r] + part[r] + fbias, 0.f);
    }
    __syncthreads();

    // ---- epilogue on ALL 16 waves: wave -> samples wv*2 + {0,1}, 4 lanes per sample ----
    if (lane < 8) {
        const int L = lane & 3;
        const int s = wv * 2 + (lane >> 2);
        const float* hfl = (const float*)(c1h + (size_t)s * 1384 + 1152);

        float a0 = 0.f, a1 = 0.f, a2 = 0.f, a3 = 0.f;
#pragma unroll
        for (int i2 = 0; i2 < 4; ++i2) {
            float4 hv = *(const float4*)(hfl + L * 16 + i2 * 4);
#pragma unroll
            for (int c = 0; c < 4; ++c) {
                int ff = L * 16 + i2 * 4 + c;
                float4 pw = *(const float4*)&prews[ff * 4];
                float hx = (c == 0) ? hv.x : (c == 1) ? hv.y : (c == 2) ? hv.z : hv.w;
                a0 = fmaf(hx, pw.x, a0);
                a1 = fmaf(hx, pw.y, a1);
                a2 = fmaf(hx, pw.z, a2);
                a3 = fmaf(hx, pw.w, a3);
            }
        }
        a0 += __shfl_xor(a0, 1); a0 += __shfl_xor(a0, 2);
        a1 += __shfl_xor(a1, 1); a1 += __shfl_xor(a1, 2);
        a2 += __shfl_xor(a2, 1); a2 += __shfl_xor(a2, 2);
        a3 += __shfl_xor(a3, 1); a3 += __shfl_xor(a3, 2);

        const float HP = 1.5707963267948966f;
        float qin[4] = { tanhf(a0 + preb[0]) * HP, tanhf(a1 + preb[1]) * HP,
                         tanhf(a2 + preb[2]) * HP, tanhf(a3 + preb[3]) * HP };

        float va[4], vb[4];
        const float RS = 0.70710678118654752f;
#pragma unroll
        for (int w = 0; w < 4; ++w) {
            float sw, cw;
            sincosf(qin[w] * 0.5f, &sw, &cw);
            va[w] = (cw - sw) * RS;
            vb[w] = (sw + cw) * RS;
        }
        float sv[16];
#pragma unroll
        for (int jj = 0; jj < 16; ++jj) {
            float t = (jj & 8) ? vb[0] : va[0];
            t *= (jj & 4) ? vb[1] : va[1];
            t *= (jj & 2) ? vb[2] : va[2];
            t *= (jj & 1) ? vb[3] : va[3];
            sv[jj] = t;
        }
        float z0 = 0.f, z1 = 0.f, z2 = 0.f, z3 = 0.f;
#pragma unroll
        for (int rr = 0; rr < 4; ++rr) {
            const int r = L * 4 + rr;
            float m = 0.f;
#pragma unroll
            for (int jj = 0; jj < 16; ++jj) m = fmaf(Ms[r][jj], sv[jj], m);
            float p = m * m;
            z0 += (r & 8) ? -p : p;
            z1 += (r & 4) ? -p : p;
            z2 += (r & 2) ? -p : p;
            z3 += (r & 1) ? -p : p;
        }
        z0 += __shfl_xor(z0, 1); z0 += __shfl_xor(z0, 2);
        z1 += __shfl_xor(z1, 1); z1 += __shfl_xor(z1, 2);
        z2 += __shfl_xor(z2, 1); z2 += __shfl_xor(z2, 2);
        z3 += __shfl_xor(z3, 1); z3 += __shfl_xor(z3, 2);

        if (L == 0) {
            float t = postb[0] + z0 * postw[0] + z1 * postw[1] + z2 * postw[2] + z3 * postw[3];
            out[bs + s] = 1.f / (1.f + expf(-t));
        }
    }
}

extern "C" void kernel_launch(void* const* d_in, const int* in_sizes, int n_in,
                              void* d_out, int out_size, void* d_ws, size_t ws_size,
                              hipStream_t stream) {
    const float* x     = (const float*)d_in[0];
    const float* w1    = (const float*)d_in[1];
    const float* b1    = (const float*)d_in[2];
    const float* w2    = (const float*)d_in[3];
    const float* b2    = (const float*)d_in[4];
    const float* fcw   = (const float*)d_in[5];
    const float* fcb   = (const float*)d_in[6];
    const float* prew  = (const float*)d_in[7];
    const float* preb  = (const float*)d_in[8];
    const float* qp    = (const float*)d_in[9];
    const float* postw = (const float*)d_in[10];
    const float* postb = (const float*)d_in[11];
    float* out = (float*)d_out;

    u16*   fwhi = (u16*)d_ws;                           // 128 KiB
    u16*   fwlo = fwhi + 65536;                         // 128 KiB
    float* Mg   = (float*)((char*)d_ws + 262144);       // 1 KiB
    u16*   w2b  = (u16*)((char*)d_ws + 263168);         // 12 KiB

    const int B = in_sizes[0] / 64;   // 32768

    prep_kernel<<<dim3(64), dim3(256), 0, stream>>>(fcw, w2, qp, fwhi, fwlo, w2b, Mg);
    fused_kernel<<<dim3(B / 32), dim3(1024), 0, stream>>>(x, w1, b1, w2b, b2,
                                                          fwhi, fwlo, fcb, prew, preb,
                                                          postw, postb, Mg, out);
}

// Round 11
// 146.424 us; speedup vs baseline: 1.2917x; 1.2917x over previous
//
#include <hip/hip_runtime.h>
#include <math.h>

typedef unsigned short u16;
typedef unsigned int u32;
typedef __attribute__((ext_vector_type(8))) short bf16x8;   // 8 bf16 = 4 VGPR (MFMA A/B frag)
typedef __attribute__((ext_vector_type(4))) float f32x4;    // MFMA C/D frag

__device__ __forceinline__ u16 f32_to_bf16(float f) {
    u32 u = __float_as_uint(f);
    u32 r = u + 0x7FFFu + ((u >> 16) & 1u);   // round-to-nearest-even
    return (u16)(r >> 16);
}
__device__ __forceinline__ u32 pack2(u16 a, u16 b) { return (u32)a | ((u32)b << 16); }

// RNE-rounded bf16 pair pack via v_perm
__device__ __forceinline__ u32 rne_bits(float f) {
    u32 u = __float_as_uint(f);
    return u + 0x7FFFu + ((u >> 16) & 1u);
}
__device__ __forceinline__ u32 pack_rne(float a, float b) {
    return __builtin_amdgcn_perm(rne_bits(b), rne_bits(a), 0x07060302u);
}

// fast tanh / sigmoid via hardware exp
__device__ __forceinline__ float fast_tanh(float x) {
    float e = __expf(2.f * x);
    return 1.f - 2.f / (e + 1.f);
}

// ---------------- quantum gate helpers (prep only; precise libm) ----------------
template<int STRIDE>
__device__ __forceinline__ void ry_gate(float st[16], float theta) {
    float s, c;
    sincosf(theta * 0.5f, &s, &c);
#pragma unroll
    for (int i = 0; i < 16; ++i) {
        if (i & STRIDE) continue;
        float s0 = st[i], s1 = st[i | STRIDE];
        st[i]          = c * s0 - s * s1;
        st[i | STRIDE] = fmaf(s, s0, c * s1);
    }
}
template<int CS, int TS>
__device__ __forceinline__ void cnot_gate(float st[16]) {
#pragma unroll
    for (int i = 0; i < 16; ++i) {
        if ((i & CS) && !(i & TS)) {
            float tmp = st[i]; st[i] = st[i | TS]; st[i | TS] = tmp;
        }
    }
}

// ---------------- Prep: fcw transpose->bf16, w2->bf16 frag layout, circuit matrix M ----------
// whi: [f][k = op*64+oc] (k_ref = oc*16+op). w2b: [(t*64+oc)*32+ic] bf16.
__global__ __launch_bounds__(256) void prep_kernel(
    const float* __restrict__ fcw, const float* __restrict__ w2,
    const float* __restrict__ qp,
    u16* __restrict__ whi, u16* __restrict__ w2b, float* __restrict__ Mg)
{
    const int f  = blockIdx.x;         // 0..63
    const int k0 = threadIdx.x * 4;    // 0..1020
    u16 hv[4];
#pragma unroll
    for (int i = 0; i < 4; ++i) {
        int k  = k0 + i;
        int op = k >> 6, oc = k & 63;
        hv[i] = f32_to_bf16(fcw[(size_t)(oc * 16 + op) * 64 + f]);
    }
    *(uint2*)(whi + (size_t)f * 1024 + k0) = make_uint2(pack2(hv[0], hv[1]), pack2(hv[2], hv[3]));

    if (threadIdx.x < 96) {
        const int j  = threadIdx.x;
        const int ic = j / 3, t = j - ic * 3;
        w2b[(t * 64 + f) * 32 + ic] = f32_to_bf16(w2[f * 96 + j]);
    }

    if (blockIdx.x == 0 && threadIdx.x < 16) {
        const int j = threadIdx.x;
        float st[16];
#pragma unroll
        for (int i = 0; i < 16; ++i) st[i] = (i == j) ? 1.f : 0.f;
        for (int k = 0; k < 6; ++k) {
            cnot_gate<8, 4>(st);   // CNOT(0,1)
            cnot_gate<2, 1>(st);   // CNOT(2,3)
            cnot_gate<4, 2>(st);   // CNOT(1,2)
            ry_gate<8>(st, qp[k * 4 + 0]);
            ry_gate<4>(st, qp[k * 4 + 1]);
            ry_gate<2>(st, qp[k * 4 + 2]);
            ry_gate<1>(st, qp[k * 4 + 3]);
        }
#pragma unroll
        for (int i = 0; i < 16; ++i) Mg[i * 16 + j] = st[i];
    }
}

// ---------------- Fused: conv1 -> conv2(MFMA) -> fc(MFMA) -> quantum epilogue ----------------
// R8 champion geometry: 32 samples/block, 1024 blocks, 1024 threads (16 waves), ~91 KB LDS
// -> 1 block/CU. __launch_bounds__(1024,4) -> VGPR cap 128 (loose cap = no spill, R8-proven;
// diagnostic: WRITE_SIZE must stay ~0.13 MB). R11 deltas vs R8: fc single-bf16 weights
// (halved MFMA chain + B-stream), epilogue on all 16 waves, fast transcendentals.
// Per-sample block in c1h (1384 u16): c1T rows p[0,34) stride 40 (halo rows 0,33 zero);
// hT aliased (in-wave read-before-write) op-chunk stride 72; hfl f32[64] at u16 offset 1152.
__global__ __launch_bounds__(1024, 4) void fused_kernel(
    const float* __restrict__ x,
    const float* __restrict__ w1, const float* __restrict__ b1,
    const u16* __restrict__ w2b, const float* __restrict__ b2,
    const u16* __restrict__ whi,
    const float* __restrict__ fcb,
    const float* __restrict__ prew, const float* __restrict__ preb,
    const float* __restrict__ postw, const float* __restrict__ postb,
    const float* __restrict__ Mg,
    float* __restrict__ out)
{
    __shared__ __align__(16) u16 c1h[32 * 1384];   // 88.6 KB
    __shared__ float prews[256];                   // 1 KB
    __shared__ float Ms[16][17];                   // 1.1 KB

    const int tid  = threadIdx.x;
    const int bs   = blockIdx.x * 32;
    const int wv   = tid >> 6, lane = tid & 63;
    const int lr   = lane & 15, lq = lane >> 4;

    // ---- stage small tables ----
    if (tid < 256) {
        prews[tid] = prew[tid];
        Ms[tid >> 4][tid & 15] = Mg[tid];
    }

    // ---- conv1 + relu + pool2 -> c1T; thread = (sample, p-row), exactly 32x32 = 1024 ----
    {
        const int s1 = tid >> 5;        // 0..31
        const int pp = tid & 31;        // p = pp+1
        const float* xb = x + (size_t)(bs + s1) * 64;
        const int j = 2 * pp;
        float xm1 = (j == 0)  ? 0.f : xb[j - 1];
        float x0  = xb[j];
        float x1  = xb[j + 1];
        float xp2 = (j == 62) ? 0.f : xb[j + 2];

        u16* sbase = c1h + s1 * 1384;
        if (pp == 0 || pp == 31) {      // halo rows 0 and 33
            uint4 z = make_uint4(0, 0, 0, 0);
            uint4* zr = (uint4*)(sbase + (pp == 0 ? 0 : 33) * 40);
            zr[0] = z; zr[1] = z; zr[2] = z; zr[3] = z;
        }
        u32 row[16];
#pragma unroll
        for (int icp = 0; icp < 16; ++icp) {
            float v[2];
#pragma unroll
            for (int h2 = 0; h2 < 2; ++h2) {
                int ic = icp * 2 + h2;
                // wave-uniform indices -> scalar loads on the s-pipe
                float wa = w1[ic * 3], wb = w1[ic * 3 + 1], wc = w1[ic * 3 + 2], bb = b1[ic];
                float y0 = bb + wa * xm1 + wb * x0 + wc * x1;
                float y1 = bb + wa * x0  + wb * x1 + wc * xp2;
                v[h2] = fmaxf(fmaxf(y0, y1), 0.f);
            }
            row[icp] = pack_rne(v[0], v[1]);
        }
        uint4* d = (uint4*)(sbase + (1 + pp) * 40);
        d[0] = make_uint4(row[0],  row[1],  row[2],  row[3]);
        d[1] = make_uint4(row[4],  row[5],  row[6],  row[7]);
        d[2] = make_uint4(row[8],  row[9],  row[10], row[11]);
        d[3] = make_uint4(row[12], row[13], row[14], row[15]);
    }

    // ---- conv2 resident frags: all 3 taps (48 VGPR) + bias (16 VGPR), from L2;
    //      issued after conv1 stores so the latency overlaps the barrier wait ----
    bf16x8 af[3][4];
#pragma unroll
    for (int t = 0; t < 3; ++t)
#pragma unroll
        for (int mt = 0; mt < 4; ++mt)
            af[t][mt] = *(const bf16x8*)(w2b + (size_t)(t * 64 + mt * 16 + lr) * 32 + lq * 8);
    f32x4 bias2[4];
#pragma unroll
    for (int mt = 0; mt < 4; ++mt)
        bias2[mt] = *(const f32x4*)(b2 + mt * 16 + lq * 4);
    __syncthreads();

    // ---- conv2 via MFMA (bias as C-init) + pool -> hT aliased into c1h ----
#pragma unroll
    for (int nt = 0; nt < 4; ++nt) {              // wave wv -> samples 2wv, 2wv+1; two q-halves
        const int s  = wv * 2 + (nt >> 1);
        const int qb = (nt & 1) * 16;
        const u16* bp = c1h + s * 1384 + (qb + lr) * 40 + lq * 8;
        bf16x8 bf0 = *(const bf16x8*)(bp);        // tap t=0
        bf16x8 bf1 = *(const bf16x8*)(bp + 40);   // t=1 (+1 row)
        bf16x8 bf2 = *(const bf16x8*)(bp + 80);   // t=2 (+2 rows)
        const int op = (qb + lr) >> 1;
#pragma unroll
        for (int mt = 0; mt < 4; ++mt) {          // interleaved epilogue: acc live = 4
            f32x4 acc = __builtin_amdgcn_mfma_f32_16x16x32_bf16(af[0][mt], bf0, bias2[mt], 0, 0, 0);
            acc = __builtin_amdgcn_mfma_f32_16x16x32_bf16(af[1][mt], bf1, acc, 0, 0, 0);
            acc = __builtin_amdgcn_mfma_f32_16x16x32_bf16(af[2][mt], bf2, acc, 0, 0, 0);
            float p0 = fmaxf(fmaxf(acc[0], __shfl_xor(acc[0], 1)), 0.f);
            float p1 = fmaxf(fmaxf(acc[1], __shfl_xor(acc[1], 1)), 0.f);
            float p2 = fmaxf(fmaxf(acc[2], __shfl_xor(acc[2], 1)), 0.f);
            float p3 = fmaxf(fmaxf(acc[3], __shfl_xor(acc[3], 1)), 0.f);
            if (!(lane & 1)) {
                *(uint2*)(c1h + s * 1384 + op * 72 + mt * 16 + lq * 4) =
                    make_uint2(pack_rne(p0, p1), pack_rne(p2, p3));
            }
        }
    }
    __syncthreads();

    // ---- fc via MFMA on waves 0-3: each wave streams B ONCE (single bf16, 128 KB/block),
    //      applies it to both 16-sample A-tiles ----
    if (wv < 4) {
        const int n0 = wv * 16;
        const float fbias = fcb[n0 + lr];
        f32x4 facc0 = {0.f, 0.f, 0.f, 0.f};
        f32x4 facc1 = {0.f, 0.f, 0.f, 0.f};
        const u16* ab0 = c1h + (size_t)lr * 1384 + lq * 8;
        const u16* ab1 = c1h + (size_t)(16 + lr) * 1384 + lq * 8;
        const u16* bh  = whi + (size_t)(n0 + lr) * 1024 + lq * 8;
#pragma unroll 8
        for (int kc = 0; kc < 32; ++kc) {
            const int aoff = (kc >> 1) * 72 + (kc & 1) * 32;
            bf16x8 a0 = *(const bf16x8*)(ab0 + aoff);
            bf16x8 a1 = *(const bf16x8*)(ab1 + aoff);
            bf16x8 fh = *(const bf16x8*)(bh + kc * 32);
            facc0 = __builtin_amdgcn_mfma_f32_16x16x32_bf16(a0, fh, facc0, 0, 0, 0);
            facc1 = __builtin_amdgcn_mfma_f32_16x16x32_bf16(a1, fh, facc1, 0, 0, 0);
        }
        // D: row = lq*4+r = sample-in-tile, col = n0+lr; per-sample hfl slot (disjoint from hT)
#pragma unroll
        for (int r = 0; r < 4; ++r) {
            ((float*)(c1h + (size_t)(lq * 4 + r) * 1384 + 1152))[n0 + lr] =
                fmaxf(facc0[r] + fbias, 0.f);
            ((float*)(c1h + (size_t)(16 + lq * 4 + r) * 1384 + 1152))[n0 + lr] =
                fmaxf(facc1[r] + fbias, 0.f);
        }
    }
    __syncthreads();

    // ---- epilogue on ALL 16 waves: wave -> samples wv*2 + {0,1}, 4 lanes per sample ----
    if (lane < 8) {
        const int L = lane & 3;
        const int s = wv * 2 + (lane >> 2);
        const float* hfl = (const float*)(c1h + (size_t)s * 1384 + 1152);

        float a0 = 0.f, a1 = 0.f, a2 = 0.f, a3 = 0.f;
#pragma unroll
        for (int i2 = 0; i2 < 4; ++i2) {
            float4 hv = *(const float4*)(hfl + L * 16 + i2 * 4);
#pragma unroll
            for (int c = 0; c < 4; ++c) {
                int ff = L * 16 + i2 * 4 + c;
                float4 pw = *(const float4*)&prews[ff * 4];
                float hx = (c == 0) ? hv.x : (c == 1) ? hv.y : (c == 2) ? hv.z : hv.w;
                a0 = fmaf(hx, pw.x, a0);
                a1 = fmaf(hx, pw.y, a1);
                a2 = fmaf(hx, pw.z, a2);
                a3 = fmaf(hx, pw.w, a3);
            }
        }
        a0 += __shfl_xor(a0, 1); a0 += __shfl_xor(a0, 2);
        a1 += __shfl_xor(a1, 1); a1 += __shfl_xor(a1, 2);
        a2 += __shfl_xor(a2, 1); a2 += __shfl_xor(a2, 2);
        a3 += __shfl_xor(a3, 1); a3 += __shfl_xor(a3, 2);

        const float HP = 1.5707963267948966f;
        float qin[4] = { fast_tanh(a0 + preb[0]) * HP, fast_tanh(a1 + preb[1]) * HP,
                         fast_tanh(a2 + preb[2]) * HP, fast_tanh(a3 + preb[3]) * HP };

        float va[4], vb[4];
        const float RS = 0.70710678118654752f;
#pragma unroll
        for (int w = 0; w < 4; ++w) {
            float sw, cw;
            __sincosf(qin[w] * 0.5f, &sw, &cw);
            va[w] = (cw - sw) * RS;
            vb[w] = (sw + cw) * RS;
        }
        float sv[16];
#pragma unroll
        for (int jj = 0; jj < 16; ++jj) {
            float t = (jj & 8) ? vb[0] : va[0];
            t *= (jj & 4) ? vb[1] : va[1];
            t *= (jj & 2) ? vb[2] : va[2];
            t *= (jj & 1) ? vb[3] : va[3];
            sv[jj] = t;
        }
        float z0 = 0.f, z1 = 0.f, z2 = 0.f, z3 = 0.f;
#pragma unroll
        for (int rr = 0; rr < 4; ++rr) {
            const int r = L * 4 + rr;
            float m = 0.f;
#pragma unroll
            for (int jj = 0; jj < 16; ++jj) m = fmaf(Ms[r][jj], sv[jj], m);
            float p = m * m;
            z0 += (r & 8) ? -p : p;
            z1 += (r & 4) ? -p : p;
            z2 += (r & 2) ? -p : p;
            z3 += (r & 1) ? -p : p;
        }
        z0 += __shfl_xor(z0, 1); z0 += __shfl_xor(z0, 2);
        z1 += __shfl_xor(z1, 1); z1 += __shfl_xor(z1, 2);
        z2 += __shfl_xor(z2, 1); z2 += __shfl_xor(z2, 2);
        z3 += __shfl_xor(z3, 1); z3 += __shfl_xor(z3, 2);

        if (L == 0) {
            float t = postb[0] + z0 * postw[0] + z1 * postw[1] + z2 * postw[2] + z3 * postw[3];
            out[bs + s] = 1.f / (1.f + __expf(-t));
        }
    }
}

extern "C" void kernel_launch(void* const* d_in, const int* in_sizes, int n_in,
                              void* d_out, int out_size, void* d_ws, size_t ws_size,
                              hipStream_t stream) {
    const float* x     = (const float*)d_in[0];
    const float* w1    = (const float*)d_in[1];
    const float* b1    = (const float*)d_in[2];
    const float* w2    = (const float*)d_in[3];
    const float* b2    = (const float*)d_in[4];
    const float* fcw   = (const float*)d_in[5];
    const float* fcb   = (const float*)d_in[6];
    const float* prew  = (const float*)d_in[7];
    const float* preb  = (const float*)d_in[8];
    const float* qp    = (const float*)d_in[9];
    const float* postw = (const float*)d_in[10];
    const float* postb = (const float*)d_in[11];
    float* out = (float*)d_out;

    u16*   fwhi = (u16*)d_ws;                           // 64*1024 bf16 = 128 KiB
    float* Mg   = (float*)((char*)d_ws + 131072);       // 1 KiB
    u16*   w2b  = (u16*)((char*)d_ws + 132096);         // 12 KiB

    const int B = in_sizes[0] / 64;   // 32768

    prep_kernel<<<dim3(64), dim3(256), 0, stream>>>(fcw, w2, qp, fwhi, w2b, Mg);
    fused_kernel<<<dim3(B / 32), dim3(1024), 0, stream>>>(x, w1, b1, w2b, b2,
                                                          fwhi, fcb, prew, preb,
                                                          postw, postb, Mg, out);
}